// Round 9
// baseline (95.016 us; speedup 1.0000x reference)
//
#include <hip/hip_runtime.h>

// GSICell. out[n] = sum_{e: dst=n} eattr[s%100, d%100] * <feat38(x_i,x_j), wc_eff> + <feat12(x[n]), wf_eff>
// wc_eff[k] = c_mask[k]*(wc2[k]-wc2[k+38]); wf_eff[k] = f_mask[k]*(wf2[k]-wf2[k+12])
//
// R8 post-mortem: 90.7us; kernels ~25us, edge kernel latency-bound (R7 showed total
// VALU work ~5us). At 16 waves/CU the ~1400cyc load->gather->math chain is only
// borderline hidden. R9: B=512 x 1024thr = 2 blocks/CU, 32 waves/CU (max), 2 edges/
// thread via int2 index loads. LDS 2x41KB=82KB fits; scratch 20MB.

#define NCL 38
#define NFL 12
#define NMAX 10240
#define GRP 4          // thread-groups per reduce block (each sums B/GRP rows)

__device__ __forceinline__ float frcp(float v) { return __builtin_amdgcn_rcpf(v); }

// _safe_inv: 1.0 / (|v|<eps ? sign(v)*eps : v), eps=1e-2, sign(0)=+1
__device__ __forceinline__ float safe_inv(float v) {
    float den = (fabsf(v) < 0.01f) ? ((v >= 0.0f) ? 0.01f : -0.01f) : v;
    return frcp(den);
}

// 38-term edge library dotted with wc_eff on the fly (w = LDS pointer).
__device__ __forceinline__ float edge_msg(float xi, float xj, const float* w) {
    float d = xj - xi;
    float s = xj + xi;
    float acc;
    acc  = w[0] * xi + w[1] * xj + w[2] * d;
    acc += w[3] * (xi * xi) + w[4] * (xj * xj) + w[5] * (d * d);
    float ii = safe_inv(xi), ij = safe_inv(xj), id = safe_inv(d), is = safe_inv(s);
    acc += w[6] * ii + w[7] * ij + w[8] * id + w[9] * is;
    acc += w[10] * (ii * ii) + w[11] * (ij * ij) + w[12] * (id * id) + w[13] * (is * is);
    float sd = __sinf(d), cd = __cosf(d);
    float ss = __sinf(s), cs = __cosf(s);
    float si = __sinf(xi), ci = __cosf(xi);
    float sj = __sinf(xj), cj = __cosf(xj);
    acc += w[14] * sd + w[15] * cd + w[16] * ss + w[17] * cs;
    acc += w[18] * si + w[19] * ci + w[20] * sj + w[21] * cj;
    acc += w[22] * (xi * xj) + w[23] * (xi * sj) + w[24] * (xj * si) + w[25] * (sd * cs);
    {
        float e = __expf(xi), e2 = e * e;
        acc += w[26] * ((e2 - 1.f) * frcp(e2 + 1.f)) + w[27] * (e * frcp(e + 1.f)) + w[28] * fmaxf(xi, 0.f);
    }
    {
        float e = __expf(xj), e2 = e * e;
        acc += w[29] * ((e2 - 1.f) * frcp(e2 + 1.f)) + w[30] * (e * frcp(e + 1.f)) + w[31] * fmaxf(xj, 0.f);
    }
    {
        float e = __expf(d), e2 = e * e;
        acc += w[32] * ((e2 - 1.f) * frcp(e2 + 1.f)) + w[33] * (e * frcp(e + 1.f)) + w[34] * fmaxf(d, 0.f);
    }
    {
        float e = __expf(s), e2 = e * e;
        acc += w[35] * ((e2 - 1.f) * frcp(e2 + 1.f)) + w[36] * (e * frcp(e + 1.f)) + w[37] * fmaxf(s, 0.f);
    }
    return acc;
}

// Node library: [1, sin, cos, x*sin, x, x^2, inv, inv^2, inv^3, tanh, sigmoid, relu]
__device__ __forceinline__ float node_F(float v, const float* wf) {
    float sv = __sinf(v), cv = __cosf(v);
    float iv = safe_inv(v);
    float e  = __expf(v), e2 = e * e;
    float th = (e2 - 1.f) * frcp(e2 + 1.f);
    float sg = e * frcp(e + 1.f);
    return wf[0] + wf[1] * sv + wf[2] * cv + wf[3] * (v * sv)
         + wf[4] * v + wf[5] * (v * v)
         + wf[6] * iv + wf[7] * (iv * iv) + wf[8] * (iv * iv * iv)
         + wf[9] * th + wf[10] * sg + wf[11] * fmaxf(v, 0.f);
}

// ---------------- Kernel 1: edge accumulation into per-block LDS ----------------
// 2 edges/thread (int2 loads) so B=512 keeps every block busy; 2 blocks/CU.

__global__ void __launch_bounds__(1024) edge_lds_kernel(
        const float* __restrict__ x,
        const int* __restrict__ ei,           // [2, E] int32
        const float* __restrict__ eattr,      // [100, 100]
        const float* __restrict__ c_mask,
        const float* __restrict__ wc2,
        float* __restrict__ scratch,          // [gridDim.x, N] partials
        int E, int N) {
    __shared__ float w[NCL];
    __shared__ float acc[NMAX];               // 40 KB accumulator
    if (threadIdx.x < NCL)
        w[threadIdx.x] = c_mask[threadIdx.x] * (wc2[threadIdx.x] - wc2[threadIdx.x + NCL]);
    {   // vectorized zero-init (NMAX % 4 == 0)
        float4* a4 = (float4*)acc;
        for (int i = threadIdx.x; i < NMAX / 4; i += 1024) a4[i] = make_float4(0.f, 0.f, 0.f, 0.f);
    }
    __syncthreads();

    const int T = gridDim.x * 1024;
    const int t = blockIdx.x * 1024 + threadIdx.x;
    const int E2 = E & ~1;
    for (int e0 = 2 * t; e0 < E2; e0 += 2 * T) {
        int2 s2 = *(const int2*)(ei + e0);        // 8B coalesced
        int2 d2 = *(const int2*)(ei + E + e0);    // E % 2 == 0 -> aligned
        int ss[2] = {s2.x, s2.y};
        int dd[2] = {d2.x, d2.y};
#pragma unroll
        for (int k = 0; k < 2; ++k) {
            int s = ss[k], d = dd[k];
            float m  = edge_msg(x[d], x[s], w);             // L1/L2-resident gathers
            float ea = eattr[(s % 100) * 100 + (d % 100)];
            atomicAdd(&acc[d], ea * m);                     // ds_add_f32
        }
    }
    if (t == 0 && (E & 1)) {                       // tail (E odd), usually empty
        int e = E - 1;
        int s = ei[e], d = ei[E + e];
        float m  = edge_msg(x[d], x[s], w);
        float ea = eattr[(s % 100) * 100 + (d % 100)];
        atomicAdd(&acc[d], ea * m);
    }
    __syncthreads();
    // coalesced float4 flush
    float4* dst4 = (float4*)(scratch + (size_t)blockIdx.x * N);
    const float4* a4 = (const float4*)acc;
    int n4 = N / 4;
    for (int i = threadIdx.x; i < n4; i += 1024) dst4[i] = a4[i];
    for (int i = 4 * n4 + threadIdx.x; i < N; i += 1024)
        scratch[(size_t)blockIdx.x * N + i] = acc[i];
}

// ---------------- Kernel 2: fused reduction + node library + out write ----------------
// Block = 256 threads = 64 node-columns x GRP row-groups. Each thread sums B/GRP
// partial rows (coalesced 256B lines per iteration), LDS-reduce GRP->1, add node_F.

__global__ void __launch_bounds__(256) reduce_fused_kernel(
        const float* __restrict__ scratch,    // [B][N]
        const float* __restrict__ x,
        const float* __restrict__ f_mask,
        const float* __restrict__ wf2,
        float* __restrict__ out, int N, int B) {
    __shared__ float wf[NFL];
    __shared__ float part[GRP][64];
    if (threadIdx.x < NFL)
        wf[threadIdx.x] = f_mask[threadIdx.x] * (wf2[threadIdx.x] - wf2[threadIdx.x + NFL]);

    const int lane = threadIdx.x & 63;        // node column within block
    const int g    = threadIdx.x >> 6;        // row group
    const int n    = blockIdx.x * 64 + lane;
    const int per  = B / GRP;

    float sum = 0.f;
    if (n < N) {
        const float* p = scratch + (size_t)(g * per) * N + n;
#pragma unroll 8
        for (int b = 0; b < per; ++b) sum += p[(size_t)b * N];   // coalesced per iter
    }
    part[g][lane] = sum;
    __syncthreads();
    if (g == 0 && n < N) {
        float tot = node_F(x[n], wf);
#pragma unroll
        for (int gg = 0; gg < GRP; ++gg) tot += part[gg][lane];
        out[n] = tot;
    }
}

// ---------------- Fallback path (R3, proven): global hw atomics ----------------

__global__ void __launch_bounds__(256) node_kernel(
        const float* __restrict__ x,
        const float* __restrict__ f_mask,
        const float* __restrict__ wf2,
        float* __restrict__ out, int n) {
    __shared__ float wf[NFL];
    if (threadIdx.x < NFL)
        wf[threadIdx.x] = f_mask[threadIdx.x] * (wf2[threadIdx.x] - wf2[threadIdx.x + NFL]);
    __syncthreads();
    int i = blockIdx.x * blockDim.x + threadIdx.x;
    if (i >= n) return;
    out[i] = node_F(x[i], wf);
}

__global__ void __launch_bounds__(256) edge_atomic_kernel(
        const float* __restrict__ x,
        const int* __restrict__ ei,
        const float* __restrict__ eattr,
        const float* __restrict__ c_mask,
        const float* __restrict__ wc2,
        float* __restrict__ out,
        int E) {
    __shared__ float w[NCL];
    if (threadIdx.x < NCL)
        w[threadIdx.x] = c_mask[threadIdx.x] * (wc2[threadIdx.x] - wc2[threadIdx.x + NCL]);
    __syncthreads();
    int t  = blockIdx.x * blockDim.x + threadIdx.x;
    int e0 = 4 * t;
    if (e0 + 3 < E) {
        int4 s4 = *(const int4*)(ei + e0);
        int4 d4 = *(const int4*)(ei + E + e0);
        int ss[4] = {s4.x, s4.y, s4.z, s4.w};
        int dd[4] = {d4.x, d4.y, d4.z, d4.w};
#pragma unroll
        for (int k = 0; k < 4; ++k) {
            int s = ss[k], d = dd[k];
            float m  = edge_msg(x[d], x[s], w);
            float ea = eattr[(s % 100) * 100 + (d % 100)];
            unsafeAtomicAdd(out + d, ea * m);
        }
    } else {
        for (int e = e0; e < E; ++e) {
            int s = ei[e], d = ei[E + e];
            float m  = edge_msg(x[d], x[s], w);
            float ea = eattr[(s % 100) * 100 + (d % 100)];
            unsafeAtomicAdd(out + d, ea * m);
        }
    }
}

extern "C" void kernel_launch(void* const* d_in, const int* in_sizes, int n_in,
                              void* d_out, int out_size, void* d_ws, size_t ws_size,
                              hipStream_t stream) {
    // inputs: 0=t, 1=x[N], 2=edge_index[2*E] int32, 3=c_mask[38], 4=f_mask[12],
    //         5=wc_2[76], 6=wf_2[24], 7=edge_attr_all[100*100]
    const float* x      = (const float*)d_in[1];
    const int*   ei     = (const int*)d_in[2];
    const float* c_mask = (const float*)d_in[3];
    const float* f_mask = (const float*)d_in[4];
    const float* wc2    = (const float*)d_in[5];
    const float* wf2    = (const float*)d_in[6];
    const float* eattr  = (const float*)d_in[7];
    float* out = (float*)d_out;

    int N = in_sizes[1];
    int E = in_sizes[2] / 2;

    // pick partial-count B by available scratch: B * N * 4 bytes (B % GRP == 0)
    int B = 0;
    if (N <= NMAX) {
        const int tiers[4] = {512, 256, 128, 64};
        for (int i = 0; i < 4; ++i) {
            size_t need = (size_t)tiers[i] * (size_t)N * 4;
            if (ws_size >= need) { B = tiers[i]; break; }
        }
    }

    if (B) {
        float* scratch = (float*)d_ws;                 // [B][N]
        edge_lds_kernel<<<B, 1024, 0, stream>>>(x, ei, eattr, c_mask, wc2, scratch, E, N);
        reduce_fused_kernel<<<(N + 63) / 64, 256, 0, stream>>>(scratch, x, f_mask, wf2, out, N, B);
    } else {
        node_kernel<<<(N + 255) / 256, 256, 0, stream>>>(x, f_mask, wf2, out, N);
        int threads = (E + 3) / 4;
        edge_atomic_kernel<<<(threads + 255) / 256, 256, 0, stream>>>(x, ei, eattr, c_mask, wc2, out, E);
    }
}

// Round 10
// 89.096 us; speedup vs baseline: 1.0665x; 1.0665x over previous
//
#include <hip/hip_runtime.h>

// GSICell. out[n] = sum_{e: dst=n} eattr[s%100, d%100] * <feat38(x_i,x_j), wc_eff> + <feat12(x[n]), wf_eff>
// wc_eff[k] = c_mask[k]*(wc2[k]-wc2[k+38]); wf_eff[k] = f_mask[k]*(wf2[k]-wf2[k+12])
//
// R9 post-mortem: B=512 regressed (+4us scratch traffic, no occupancy gain) ->
// edge kernel is divergent-address-throughput bound (~1 lane-addr/cyc/pipe/CU).
// Evidence: R6 (all gathers LDS) == R8 (all gathers VMEM) exactly; 4 divergent
// ops/edge irreducible. R10: BALANCE pipes 2:2 — x staged in LDS (x[dst] via
// ds_read, acc via ds_add) while x[src] + eattr stay on VMEM. B=256, 4 edges/thr.

#define NCL 38
#define NFL 12
#define NMAX 10240
#define GRP 4          // thread-groups per reduce block (each sums B/GRP rows)

__device__ __forceinline__ float frcp(float v) { return __builtin_amdgcn_rcpf(v); }

// _safe_inv: 1.0 / (|v|<eps ? sign(v)*eps : v), eps=1e-2, sign(0)=+1
__device__ __forceinline__ float safe_inv(float v) {
    float den = (fabsf(v) < 0.01f) ? ((v >= 0.0f) ? 0.01f : -0.01f) : v;
    return frcp(den);
}

// 38-term edge library dotted with wc_eff on the fly (w = LDS pointer).
__device__ __forceinline__ float edge_msg(float xi, float xj, const float* w) {
    float d = xj - xi;
    float s = xj + xi;
    float acc;
    acc  = w[0] * xi + w[1] * xj + w[2] * d;
    acc += w[3] * (xi * xi) + w[4] * (xj * xj) + w[5] * (d * d);
    float ii = safe_inv(xi), ij = safe_inv(xj), id = safe_inv(d), is = safe_inv(s);
    acc += w[6] * ii + w[7] * ij + w[8] * id + w[9] * is;
    acc += w[10] * (ii * ii) + w[11] * (ij * ij) + w[12] * (id * id) + w[13] * (is * is);
    float sd = __sinf(d), cd = __cosf(d);
    float ss = __sinf(s), cs = __cosf(s);
    float si = __sinf(xi), ci = __cosf(xi);
    float sj = __sinf(xj), cj = __cosf(xj);
    acc += w[14] * sd + w[15] * cd + w[16] * ss + w[17] * cs;
    acc += w[18] * si + w[19] * ci + w[20] * sj + w[21] * cj;
    acc += w[22] * (xi * xj) + w[23] * (xi * sj) + w[24] * (xj * si) + w[25] * (sd * cs);
    {
        float e = __expf(xi), e2 = e * e;
        acc += w[26] * ((e2 - 1.f) * frcp(e2 + 1.f)) + w[27] * (e * frcp(e + 1.f)) + w[28] * fmaxf(xi, 0.f);
    }
    {
        float e = __expf(xj), e2 = e * e;
        acc += w[29] * ((e2 - 1.f) * frcp(e2 + 1.f)) + w[30] * (e * frcp(e + 1.f)) + w[31] * fmaxf(xj, 0.f);
    }
    {
        float e = __expf(d), e2 = e * e;
        acc += w[32] * ((e2 - 1.f) * frcp(e2 + 1.f)) + w[33] * (e * frcp(e + 1.f)) + w[34] * fmaxf(d, 0.f);
    }
    {
        float e = __expf(s), e2 = e * e;
        acc += w[35] * ((e2 - 1.f) * frcp(e2 + 1.f)) + w[36] * (e * frcp(e + 1.f)) + w[37] * fmaxf(s, 0.f);
    }
    return acc;
}

// Node library: [1, sin, cos, x*sin, x, x^2, inv, inv^2, inv^3, tanh, sigmoid, relu]
__device__ __forceinline__ float node_F(float v, const float* wf) {
    float sv = __sinf(v), cv = __cosf(v);
    float iv = safe_inv(v);
    float e  = __expf(v), e2 = e * e;
    float th = (e2 - 1.f) * frcp(e2 + 1.f);
    float sg = e * frcp(e + 1.f);
    return wf[0] + wf[1] * sv + wf[2] * cv + wf[3] * (v * sv)
         + wf[4] * v + wf[5] * (v * v)
         + wf[6] * iv + wf[7] * (iv * iv) + wf[8] * (iv * iv * iv)
         + wf[9] * th + wf[10] * sg + wf[11] * fmaxf(v, 0.f);
}

// ---------------- Kernel 1: edge accumulation, pipe-balanced 2:2 ----------------

__global__ void __launch_bounds__(1024) edge_lds_kernel(
        const float* __restrict__ x,
        const int* __restrict__ ei,           // [2, E] int32
        const float* __restrict__ eattr,      // [100, 100]
        const float* __restrict__ c_mask,
        const float* __restrict__ wc2,
        float* __restrict__ scratch,          // [gridDim.x, N] partials
        int E, int N) {
    __shared__ float w[NCL];
    __shared__ float acc[NMAX];               // 40 KB accumulator (LDS pipe: ds_add)
    __shared__ float xs[NMAX];                // 40 KB node states (LDS pipe: x[dst])
    if (threadIdx.x < NCL)
        w[threadIdx.x] = c_mask[threadIdx.x] * (wc2[threadIdx.x] - wc2[threadIdx.x + NCL]);
    {   // zero acc + stage x (coalesced float4)
        float4* a4 = (float4*)acc;
        for (int i = threadIdx.x; i < NMAX / 4; i += 1024) a4[i] = make_float4(0.f, 0.f, 0.f, 0.f);
        float4* x4 = (float4*)xs;
        int nx4 = N / 4;
        const float4* gx4 = (const float4*)x;
        for (int i = threadIdx.x; i < nx4; i += 1024) x4[i] = gx4[i];
        for (int i = 4 * nx4 + threadIdx.x; i < N; i += 1024) xs[i] = x[i];
    }
    __syncthreads();

    const int T = gridDim.x * 1024;
    const int t = blockIdx.x * 1024 + threadIdx.x;
    const int E4 = E & ~3;
    for (int e0 = 4 * t; e0 < E4; e0 += 4 * T) {
        int4 s4 = *(const int4*)(ei + e0);        // 16B coalesced
        int4 d4 = *(const int4*)(ei + E + e0);    // E % 4 == 0 -> aligned
        int ss[4] = {s4.x, s4.y, s4.z, s4.w};
        int dd[4] = {d4.x, d4.y, d4.z, d4.w};
#pragma unroll
        for (int k = 0; k < 4; ++k) {
            int s = ss[k], d = dd[k];
            float xi = xs[d];                               // LDS pipe
            float xj = x[s];                                // VMEM pipe
            float ea = eattr[(s % 100) * 100 + (d % 100)];  // VMEM pipe
            float m  = edge_msg(xi, xj, w);
            atomicAdd(&acc[d], ea * m);                     // LDS pipe (ds_add_f32)
        }
    }
    if (t == 0) {                                  // tail (E % 4), usually empty
        for (int e = E4; e < E; ++e) {
            int s = ei[e], d = ei[E + e];
            float m  = edge_msg(xs[d], x[s], w);
            float ea = eattr[(s % 100) * 100 + (d % 100)];
            atomicAdd(&acc[d], ea * m);
        }
    }
    __syncthreads();
    // coalesced float4 flush
    float4* dst4 = (float4*)(scratch + (size_t)blockIdx.x * N);
    const float4* a4 = (const float4*)acc;
    int n4 = N / 4;
    for (int i = threadIdx.x; i < n4; i += 1024) dst4[i] = a4[i];
    for (int i = 4 * n4 + threadIdx.x; i < N; i += 1024)
        scratch[(size_t)blockIdx.x * N + i] = acc[i];
}

// ---------------- Kernel 2: fused reduction + node library + out write ----------------

__global__ void __launch_bounds__(256) reduce_fused_kernel(
        const float* __restrict__ scratch,    // [B][N]
        const float* __restrict__ x,
        const float* __restrict__ f_mask,
        const float* __restrict__ wf2,
        float* __restrict__ out, int N, int B) {
    __shared__ float wf[NFL];
    __shared__ float part[GRP][64];
    if (threadIdx.x < NFL)
        wf[threadIdx.x] = f_mask[threadIdx.x] * (wf2[threadIdx.x] - wf2[threadIdx.x + NFL]);

    const int lane = threadIdx.x & 63;        // node column within block
    const int g    = threadIdx.x >> 6;        // row group
    const int n    = blockIdx.x * 64 + lane;
    const int per  = B / GRP;

    float sum = 0.f;
    if (n < N) {
        const float* p = scratch + (size_t)(g * per) * N + n;
#pragma unroll 8
        for (int b = 0; b < per; ++b) sum += p[(size_t)b * N];   // coalesced per iter
    }
    part[g][lane] = sum;
    __syncthreads();
    if (g == 0 && n < N) {
        float tot = node_F(x[n], wf);
#pragma unroll
        for (int gg = 0; gg < GRP; ++gg) tot += part[gg][lane];
        out[n] = tot;
    }
}

// ---------------- Fallback path (R3, proven): global hw atomics ----------------

__global__ void __launch_bounds__(256) node_kernel(
        const float* __restrict__ x,
        const float* __restrict__ f_mask,
        const float* __restrict__ wf2,
        float* __restrict__ out, int n) {
    __shared__ float wf[NFL];
    if (threadIdx.x < NFL)
        wf[threadIdx.x] = f_mask[threadIdx.x] * (wf2[threadIdx.x] - wf2[threadIdx.x + NFL]);
    __syncthreads();
    int i = blockIdx.x * blockDim.x + threadIdx.x;
    if (i >= n) return;
    out[i] = node_F(x[i], wf);
}

__global__ void __launch_bounds__(256) edge_atomic_kernel(
        const float* __restrict__ x,
        const int* __restrict__ ei,
        const float* __restrict__ eattr,
        const float* __restrict__ c_mask,
        const float* __restrict__ wc2,
        float* __restrict__ out,
        int E) {
    __shared__ float w[NCL];
    if (threadIdx.x < NCL)
        w[threadIdx.x] = c_mask[threadIdx.x] * (wc2[threadIdx.x] - wc2[threadIdx.x + NCL]);
    __syncthreads();
    int t  = blockIdx.x * blockDim.x + threadIdx.x;
    int e0 = 4 * t;
    if (e0 + 3 < E) {
        int4 s4 = *(const int4*)(ei + e0);
        int4 d4 = *(const int4*)(ei + E + e0);
        int ss[4] = {s4.x, s4.y, s4.z, s4.w};
        int dd[4] = {d4.x, d4.y, d4.z, d4.w};
#pragma unroll
        for (int k = 0; k < 4; ++k) {
            int s = ss[k], d = dd[k];
            float m  = edge_msg(x[d], x[s], w);
            float ea = eattr[(s % 100) * 100 + (d % 100)];
            unsafeAtomicAdd(out + d, ea * m);
        }
    } else {
        for (int e = e0; e < E; ++e) {
            int s = ei[e], d = ei[E + e];
            float m  = edge_msg(x[d], x[s], w);
            float ea = eattr[(s % 100) * 100 + (d % 100)];
            unsafeAtomicAdd(out + d, ea * m);
        }
    }
}

extern "C" void kernel_launch(void* const* d_in, const int* in_sizes, int n_in,
                              void* d_out, int out_size, void* d_ws, size_t ws_size,
                              hipStream_t stream) {
    // inputs: 0=t, 1=x[N], 2=edge_index[2*E] int32, 3=c_mask[38], 4=f_mask[12],
    //         5=wc_2[76], 6=wf_2[24], 7=edge_attr_all[100*100]
    const float* x      = (const float*)d_in[1];
    const int*   ei     = (const int*)d_in[2];
    const float* c_mask = (const float*)d_in[3];
    const float* f_mask = (const float*)d_in[4];
    const float* wc2    = (const float*)d_in[5];
    const float* wf2    = (const float*)d_in[6];
    const float* eattr  = (const float*)d_in[7];
    float* out = (float*)d_out;

    int N = in_sizes[1];
    int E = in_sizes[2] / 2;

    // pick partial-count B by available scratch: B * N * 4 bytes (B % GRP == 0)
    int B = 0;
    if (N <= NMAX) {
        const int tiers[3] = {256, 128, 64};   // B=256 proven best (R8 vs R9)
        for (int i = 0; i < 3; ++i) {
            size_t need = (size_t)tiers[i] * (size_t)N * 4;
            if (ws_size >= need) { B = tiers[i]; break; }
        }
    }

    if (B) {
        float* scratch = (float*)d_ws;                 // [B][N]
        edge_lds_kernel<<<B, 1024, 0, stream>>>(x, ei, eattr, c_mask, wc2, scratch, E, N);
        reduce_fused_kernel<<<(N + 63) / 64, 256, 0, stream>>>(scratch, x, f_mask, wf2, out, N, B);
    } else {
        node_kernel<<<(N + 255) / 256, 256, 0, stream>>>(x, f_mask, wf2, out, N);
        int threads = (E + 3) / 4;
        edge_atomic_kernel<<<(threads + 255) / 256, 256, 0, stream>>>(x, ei, eattr, c_mask, wc2, out, E);
    }
}